// Round 17
// baseline (322.414 us; speedup 1.0000x reference)
//
#include <hip/hip_runtime.h>
#include <hip/hip_bf16.h>

#define NB 8
#define NT 4096
#define NC 128
#define NH 512
#define TB 32            // output time rows per tile

typedef __attribute__((ext_vector_type(8))) short bf16x8;
typedef __attribute__((ext_vector_type(4))) float f32x4;
typedef __attribute__((ext_vector_type(16))) float f32x16;

__device__ __forceinline__ ushort f2bf(float f) {
    uint u = __float_as_uint(f);
    uint r = u + 0x7FFFu + ((u >> 16) & 1u);   // RNE (prep kernel only)
    return (ushort)(r >> 16);
}
// HW packed f32->bf16 RNE (verified R16-neutral, kept: fewer VALU ops)
__device__ __forceinline__ uint cvt_pk_bf16(float lo, float hi) {
    uint r;
    asm("v_cvt_pk_bf16_f32 %0, %1, %2" : "=v"(r) : "v"(lo), "v"(hi));
    return r;
}
__device__ __forceinline__ float bf2f(short b) {
    return __uint_as_float(((uint)(ushort)b) << 16);
}
// 32x32 C/D row for (reg, hi): row = (reg&3) + 8*(reg>>2) + 4*hi   [verified m74/m101]
__device__ __forceinline__ int rowof(int reg, int hi) {
    return (reg & 3) + 8 * (reg >> 2) + 4 * hi;
}
// ys bank-conflict swizzle (verified R9): flips short-index bits 4:5 with 7:8.
__device__ __forceinline__ int swz(int s) {
    return s ^ (((s >> 7) & 3) << 4);
}

#define NWBT 65536                    // GEMM1 B-frags (32x32 layout)
#define NWCT 131072                   // GEMM2/3 B-frags (16x16 layout, verified)

// ---- Prep: weights to bf16 in MFMA-fragment order (verified R8-R10) ----
__global__ __launch_bounds__(512) void prep_weights(
    const float* __restrict__ wb, const float* __restrict__ wres,
    const float* __restrict__ wskip, short* __restrict__ wbt32,
    short* __restrict__ wct)
{
    int i = blockIdx.x * 512 + threadIdx.x;   // [0, 196608)
    if (i < NWBT) {
        int ii = i & 7, l = (i >> 3) & 63, jt = (i >> 9) & 15, kt = i >> 13;
        int k = kt * 16 + (l >> 5) * 8 + ii;
        int j = jt * 32 + (l & 31);
        wbt32[i] = (short)f2bf(wb[(size_t)k * NH + j]);
    } else {
        int i2 = i - NWBT;                    // [0, 131072)
        int ii = i2 & 7, l = (i2 >> 3) & 63, jt = (i2 >> 9) & 15, kt = i2 >> 13;
        int k = kt * 32 + (l >> 4) * 8 + ii;
        int j = jt * 16 + (l & 15);
        float v = (j < 128) ? wres[k * NC + j] : wskip[k * NC + (j - 128)];
        wct[i2] = (short)f2bf(v);
    }
}

// ---- Fused main kernel: batch-PAIRED. One block = (pair, t0) processes
// batches b=pair and b=pair+4 sequentially; alpha/weight addresses identical
// across the two passes (cache-hot second pass), epilogue stores of pass A
// drain under GEMM1 of pass B. Bodies verbatim from verified R15/R16.
__global__ __launch_bounds__(512, 4) void conv1d_block_mfma(
    const float* __restrict__ x,      // (8,4096,128)
    const float* __restrict__ a1,     // (4096,512) f32
    const float* __restrict__ wd,     // (3,1,512)
    const float* __restrict__ a2,     // (4096,512) f32
    const short* __restrict__ wbt32,
    const short* __restrict__ wct,
    float* __restrict__ out)
{
    __shared__ short xsAB[2][8192];   // two 64x128 bf16 32x32-A-frag tiles, 32 KB
    __shared__ short ys[16384];       // 32x512 16x16-A-frags, swizzled, 32 KB

    const int tid  = threadIdx.x;
    const int lane = tid & 63;
    const int wave = tid >> 6;          // 0..7
    const int pair = blockIdx.x >> 7;   // [0,4): batches pair, pair+4
    const int t0   = (blockIdx.x & 127) * TB;
    const int hi   = lane >> 5;         // 32x32 layouts
    const int jl   = lane & 15;         // 16x16 layouts (epilogue)
    const int rb   = (lane >> 4) * 4;

    // ---- stage BOTH x tiles (rows [t0-4, t0+60), zero OOB): 2048 chunks ----
    #pragma unroll
    for (int it = 0; it < 4; ++it) {
        int g     = tid + it * 512;          // [0,2048)
        int pp    = g >> 10;
        int chunk = g & 1023;                // mt*512 + kt*64 + l
        int mt = chunk >> 9;
        int kt = (chunk >> 6) & 7;
        int l  = chunk & 63;
        int t  = t0 - 4 + mt * 32 + (l & 31);
        int c0 = kt * 16 + (l >> 5) * 8;
        int bb = pair + 4 * pp;
        float4 p0 = make_float4(0.f, 0.f, 0.f, 0.f), p1 = p0;
        if (t >= 0 && t < NT) {
            const float* src = &x[((size_t)bb * NT + t) * NC + c0];
            p0 = *reinterpret_cast<const float4*>(src);
            p1 = *reinterpret_cast<const float4*>(src + 4);
        }
        uint4 s;
        s.x = cvt_pk_bf16(p0.x, p0.y);
        s.y = cvt_pk_bf16(p0.z, p0.w);
        s.z = cvt_pk_bf16(p1.x, p1.y);
        s.w = cvt_pk_bf16(p1.z, p1.w);
        *reinterpret_cast<uint4*>(&xsAB[pp][chunk * 8]) = s;
    }
    __syncthreads();

    #pragma unroll 1
    for (int pp = 0; pp < 2; ++pp) {
        const short* xs = xsAB[pp];
        const int b = pair + 4 * pp;

        // ---- GEMM1: h(64x512) = x @ wb in 32x32x16; wave owns 64 cols ----
        f32x16 acc1[2][2];
        #pragma unroll
        for (int mt = 0; mt < 2; ++mt)
            #pragma unroll
            for (int n = 0; n < 2; ++n)
                #pragma unroll
                for (int r = 0; r < 16; ++r) acc1[mt][n][r] = 0.f;

        __builtin_amdgcn_s_setprio(1);    // T5 (verified R15: -2us)
        #pragma unroll
        for (int kt = 0; kt < 8; ++kt) {
            bf16x8 af0 = *reinterpret_cast<const bf16x8*>(&xs[((0 * 8 + kt) * 64 + lane) * 8]);
            bf16x8 af1 = *reinterpret_cast<const bf16x8*>(&xs[((1 * 8 + kt) * 64 + lane) * 8]);
            #pragma unroll
            for (int n = 0; n < 2; ++n) {
                int jt = wave * 2 + n;
                bf16x8 bfr = *reinterpret_cast<const bf16x8*>(&wbt32[((kt * 16 + jt) * 64 + lane) * 8]);
                acc1[0][n] = __builtin_amdgcn_mfma_f32_32x32x16_bf16(af0, bfr, acc1[0][n], 0, 0, 0);
                acc1[1][n] = __builtin_amdgcn_mfma_f32_32x32x16_bf16(af1, bfr, acc1[1][n], 0, 0, 0);
            }
        }
        __builtin_amdgcn_s_setprio(0);

        // ---- PReLU1, direct f32 alphas (same addresses both passes) ----
        #pragma unroll
        for (int mt = 0; mt < 2; ++mt) {
            #pragma unroll
            for (int n = 0; n < 2; ++n) {
                int j = (wave * 2 + n) * 32 + (lane & 31);
                #pragma unroll
                for (int reg = 0; reg < 16; ++reg) {
                    int t = t0 - 4 + mt * 32 + rowof(reg, hi);
                    t = min(max(t, 0), NT - 1);
                    float al = a1[(size_t)t * NH + j];
                    float v  = acc1[mt][n][reg];
                    acc1[mt][n][reg] = fmaxf(v, 0.f) + al * fminf(v, 0.f);
                }
            }
        }

        // ---- depthwise dilated conv + PReLU2 -> ys (swizzled 16x16 A-frag) ----
        float kw0[2], kw1[2], kw2[2];
        #pragma unroll
        for (int n = 0; n < 2; ++n) {
            int j = (wave * 2 + n) * 32 + (lane & 31);
            kw0[n] = wd[0 * NH + j];
            kw1[n] = wd[1 * NH + j];
            kw2[n] = wd[2 * NH + j];
        }

        #pragma unroll
        for (int n = 0; n < 2; ++n) {
            const int jt = wave * 2 + n;
            const int j  = jt * 32 + (lane & 31);
            #pragma unroll
            for (int reg = 0; reg < 16; ++reg) {
                float vm  = acc1[0][n][reg];
                float h8  = (reg < 12) ? acc1[0][n][reg + 4] : acc1[1][n][reg - 12];
                float sup = (lane < 32) ? h8 : vm;
                float h4  = __shfl_xor(sup, 32);
                float v = kw0[n] * vm + kw1[n] * h4 + kw2[n] * h8;
                float al = a2[(size_t)(t0 + rowof(reg, hi)) * NH + j];
                v = fmaxf(v, 0.f) + al * fminf(v, 0.f);
                int mt2 = reg >> 3;
                int l2  = ((reg & 3) + 8 * ((reg >> 2) & 1) + 4 * hi) | (((lane >> 3) & 3) << 4);
                ys[swz(((mt2 * 16 + jt) * 64 + l2) * 8 + (lane & 7))] =
                    (short)cvt_pk_bf16(v, v);
            }
        }
        __syncthreads();   // ys writes visible to all waves

        // ---- GEMM2/3: out(32x256) = y(32x512) @ [wres|wskip] ----
        f32x4 acc2[2][2];
        #pragma unroll
        for (int m = 0; m < 2; ++m)
            #pragma unroll
            for (int n = 0; n < 2; ++n)
                acc2[m][n] = (f32x4){0.f, 0.f, 0.f, 0.f};

        __builtin_amdgcn_s_setprio(1);
        #pragma unroll
        for (int kt = 0; kt < 16; ++kt) {
            bf16x8 A0 = *reinterpret_cast<const bf16x8*>(&ys[swz(((0 * 16 + kt) * 64 + lane) * 8)]);
            bf16x8 A1 = *reinterpret_cast<const bf16x8*>(&ys[swz(((1 * 16 + kt) * 64 + lane) * 8)]);
            #pragma unroll
            for (int n = 0; n < 2; ++n) {
                int jt = wave * 2 + n;
                bf16x8 Bf = *reinterpret_cast<const bf16x8*>(&wct[((kt * 16 + jt) * 64 + lane) * 8]);
                acc2[0][n] = __builtin_amdgcn_mfma_f32_16x16x32_bf16(A0, Bf, acc2[0][n], 0, 0, 0);
                acc2[1][n] = __builtin_amdgcn_mfma_f32_16x16x32_bf16(A1, Bf, acc2[1][n], 0, 0, 0);
            }
        }
        __builtin_amdgcn_s_setprio(0);

        // protect ys for next pass's conv writes (G2 reads are done by here)
        if (pp == 0) __syncthreads();

        // ---- epilogue: waves 0-3 -> residual (+x from LDS xs), 4-7 -> skip ----
        // Stores issue here and drain under next pass's GEMM1 (no barrier below).
        #pragma unroll
        for (int m = 0; m < 2; ++m) {
            #pragma unroll
            for (int n = 0; n < 2; ++n) {
                int j = wave * 32 + n * 16 + jl;
                #pragma unroll
                for (int reg = 0; reg < 4; ++reg) {
                    int g = m * 16 + rb + reg;
                    size_t t = (size_t)(t0 + g);
                    float v = acc2[m][n][reg];
                    if (j < 128) {
                        int r4   = g + 4;
                        int ladr = (((r4 >> 5) * 8 + (j >> 4)) * 64
                                    + ((r4 & 31) + (((j >> 3) & 1) << 5))) * 8 + (j & 7);
                        float xv = bf2f(xs[ladr]);
                        size_t idx = ((size_t)b * NT + t) * NC + j;
                        out[idx] = v + xv;
                    } else {
                        size_t idx = ((size_t)b * NT + t) * NC + (j - 128);
                        out[(size_t)NB * NT * NC + idx] = v;
                    }
                }
            }
        }
    }
}

extern "C" void kernel_launch(void* const* d_in, const int* in_sizes, int n_in,
                              void* d_out, int out_size, void* d_ws, size_t ws_size,
                              hipStream_t stream) {
    const float* x  = (const float*)d_in[0];
    const float* wb = (const float*)d_in[1];
    const float* a1 = (const float*)d_in[2];
    const float* wd = (const float*)d_in[3];
    const float* a2 = (const float*)d_in[4];
    const float* wr = (const float*)d_in[5];
    const float* wk = (const float*)d_in[6];
    float* out = (float*)d_out;

    short* wbt32 = (short*)d_ws;
    short* wct   = wbt32 + NWBT;

    prep_weights<<<dim3(384), dim3(512), 0, stream>>>(wb, wr, wk, wbt32, wct);
    // 4 batch-pairs x 128 t-tiles = 512 blocks (2/CU, unchanged occupancy)
    conv1d_block_mfma<<<dim3(4 * (NT / TB)), dim3(512), 0, stream>>>(
        x, a1, wd, a2, wbt32, wct, out);
}

// Round 18
// 44.598 us; speedup vs baseline: 7.2294x; 7.2294x over previous
//
#include <hip/hip_runtime.h>
#include <hip/hip_bf16.h>

#define NB 8
#define NT 4096
#define NC 128
#define NH 512
#define TB 32            // output time rows per block

typedef __attribute__((ext_vector_type(8))) short bf16x8;
typedef __attribute__((ext_vector_type(4))) float f32x4;
typedef __attribute__((ext_vector_type(16))) float f32x16;

__device__ __forceinline__ ushort f2bf(float f) {
    uint u = __float_as_uint(f);
    uint r = u + 0x7FFFu + ((u >> 16) & 1u);   // RNE
    return (ushort)(r >> 16);
}
__device__ __forceinline__ float bf2f(short b) {
    return __uint_as_float(((uint)(ushort)b) << 16);
}
// 32x32 C/D row for (reg, hi): row = (reg&3) + 8*(reg>>2) + 4*hi   [verified m74/m101]
__device__ __forceinline__ int rowof(int reg, int hi) {
    return (reg & 3) + 8 * (reg >> 2) + 4 * hi;
}
// ys bank-conflict swizzle (verified R9): flips short-index bits 4:5 with 7:8.
__device__ __forceinline__ int swz(int s) {
    return s ^ (((s >> 7) & 3) << 4);
}

#define NWBT 65536                    // GEMM1 B-frags (32x32 layout)
#define NWCT 131072                   // GEMM2/3 B-frags (16x16 layout, verified)

// ---- Prep: weights to bf16 in MFMA-fragment order (verified R8-R10) ----
__global__ __launch_bounds__(512) void prep_weights(
    const float* __restrict__ wb, const float* __restrict__ wres,
    const float* __restrict__ wskip, short* __restrict__ wbt32,
    short* __restrict__ wct)
{
    int i = blockIdx.x * 512 + threadIdx.x;   // [0, 196608)
    if (i < NWBT) {
        // wbt32[((kt*16+jt)*64+l)*8+ii] = wb[kt*16+(l>>5)*8+ii][jt*32+(l&31)]
        int ii = i & 7, l = (i >> 3) & 63, jt = (i >> 9) & 15, kt = i >> 13;
        int k = kt * 16 + (l >> 5) * 8 + ii;
        int j = jt * 32 + (l & 31);
        wbt32[i] = (short)f2bf(wb[(size_t)k * NH + j]);
    } else {
        // wct (16x16 B-frags): [((kt*16+jt)*64+l)*8+ii]
        int i2 = i - NWBT;                    // [0, 131072)
        int ii = i2 & 7, l = (i2 >> 3) & 63, jt = (i2 >> 9) & 15, kt = i2 >> 13;
        int k = kt * 32 + (l >> 4) * 8 + ii;
        int j = jt * 16 + (l & 15);
        float v = (j < 128) ? wres[k * NC + j] : wskip[k * NC + (j - 128)];
        wct[i2] = (short)f2bf(v);
    }
}

// ---- Fused main kernel (verified R10 structure) + T5 setprio on MFMA clusters ----
// 512 threads (8 waves), 32-row tile; GEMM1 32x32x16, GEMM2 16x16x32;
// separate xs/ys (2 barriers), swizzled ys, LDS-sourced residual x.
// NOTE (session map): this 16-waves/CU, 124/128-reg point is the measured optimum;
// tighter reg caps spill (R3/5/6/13/14/17), more waves lose load ILP (R13),
// split kernels pay y round-trip (R12), batch pairing spills (R17).
__global__ __launch_bounds__(512, 4) void conv1d_block_mfma(
    const float* __restrict__ x,      // (8,4096,128)
    const float* __restrict__ a1,     // (4096,512) f32
    const float* __restrict__ wd,     // (3,1,512)
    const float* __restrict__ a2,     // (4096,512) f32
    const short* __restrict__ wbt32,
    const short* __restrict__ wct,
    float* __restrict__ out)
{
    __shared__ short xs[8192];        // 64x128 bf16 32x32-A-frags, 16 KB (persists)
    __shared__ short ys[16384];       // 32x512 16x16-A-frags, swizzled, 32 KB

    const int tid  = threadIdx.x;
    const int lane = tid & 63;
    const int wave = tid >> 6;          // 0..7
    const int b    = blockIdx.x >> 7;   // 128 tiles per batch
    const int t0   = (blockIdx.x & 127) * TB;
    const int hi   = lane >> 5;         // 32x32 layouts
    const int jl   = lane & 15;         // 16x16 layouts (epilogue)
    const int rb   = (lane >> 4) * 4;

    // ---- stage x tile rows [t0-4, t0+60) as 32x32 A-frags (zero OOB) ----
    #pragma unroll
    for (int it = 0; it < 2; ++it) {
        int chunk = tid + it * 512;          // [0,1024): mt*512 + kt*64 + l
        int mt = chunk >> 9;
        int kt = (chunk >> 6) & 7;
        int l  = chunk & 63;
        int t  = t0 - 4 + mt * 32 + (l & 31);
        int c0 = kt * 16 + (l >> 5) * 8;
        float4 p0 = make_float4(0.f, 0.f, 0.f, 0.f), p1 = p0;
        if (t >= 0 && t < NT) {
            const float* src = &x[((size_t)b * NT + t) * NC + c0];
            p0 = *reinterpret_cast<const float4*>(src);
            p1 = *reinterpret_cast<const float4*>(src + 4);
        }
        bf16x8 s;
        s[0] = (short)f2bf(p0.x); s[1] = (short)f2bf(p0.y);
        s[2] = (short)f2bf(p0.z); s[3] = (short)f2bf(p0.w);
        s[4] = (short)f2bf(p1.x); s[5] = (short)f2bf(p1.y);
        s[6] = (short)f2bf(p1.z); s[7] = (short)f2bf(p1.w);
        *reinterpret_cast<bf16x8*>(&xs[chunk * 8]) = s;
    }
    __syncthreads();

    // ---- GEMM1: h(64x512) = x @ wb in 32x32x16; wave owns 64 cols (jt = wave*2+n) ----
    f32x16 acc1[2][2];
    #pragma unroll
    for (int mt = 0; mt < 2; ++mt)
        #pragma unroll
        for (int n = 0; n < 2; ++n)
            #pragma unroll
            for (int r = 0; r < 16; ++r) acc1[mt][n][r] = 0.f;

    __builtin_amdgcn_s_setprio(1);    // T5: favor MFMA-issuing waves (staggered blocks)
    #pragma unroll
    for (int kt = 0; kt < 8; ++kt) {
        bf16x8 af0 = *reinterpret_cast<const bf16x8*>(&xs[((0 * 8 + kt) * 64 + lane) * 8]);
        bf16x8 af1 = *reinterpret_cast<const bf16x8*>(&xs[((1 * 8 + kt) * 64 + lane) * 8]);
        #pragma unroll
        for (int n = 0; n < 2; ++n) {
            int jt = wave * 2 + n;
            bf16x8 bfr = *reinterpret_cast<const bf16x8*>(&wbt32[((kt * 16 + jt) * 64 + lane) * 8]);
            acc1[0][n] = __builtin_amdgcn_mfma_f32_32x32x16_bf16(af0, bfr, acc1[0][n], 0, 0, 0);
            acc1[1][n] = __builtin_amdgcn_mfma_f32_32x32x16_bf16(af1, bfr, acc1[1][n], 0, 0, 0);
        }
    }
    __builtin_amdgcn_s_setprio(0);

    // ---- PReLU1, direct f32 alphas (OOB h rows are exactly 0; alpha irrelevant) ----
    #pragma unroll
    for (int mt = 0; mt < 2; ++mt) {
        #pragma unroll
        for (int n = 0; n < 2; ++n) {
            int j = (wave * 2 + n) * 32 + (lane & 31);
            #pragma unroll
            for (int reg = 0; reg < 16; ++reg) {
                int t = t0 - 4 + mt * 32 + rowof(reg, hi);
                t = min(max(t, 0), NT - 1);
                float al = a1[(size_t)t * NH + j];
                float v  = acc1[mt][n][reg];
                acc1[mt][n][reg] = fmaxf(v, 0.f) + al * fminf(v, 0.f);
            }
        }
    }
    // NO barrier: xs/ys disjoint; conv depends only on own registers.

    // ---- depthwise dilated conv + PReLU2 -> ys (16x16 A-frag layout, swizzled) ----
    //   h8 = reg<12 ? acc1[0][reg+4] : acc1[1][reg-12]         (in-lane)
    //   h4 = shfl_xor(lane<32 ? h8 : vm, 32)                   (one swap)
    float kw0[2], kw1[2], kw2[2];
    #pragma unroll
    for (int n = 0; n < 2; ++n) {
        int j = (wave * 2 + n) * 32 + (lane & 31);
        kw0[n] = wd[0 * NH + j];
        kw1[n] = wd[1 * NH + j];
        kw2[n] = wd[2 * NH + j];
    }

    #pragma unroll
    for (int n = 0; n < 2; ++n) {
        const int jt = wave * 2 + n;
        const int j  = jt * 32 + (lane & 31);
        #pragma unroll
        for (int reg = 0; reg < 16; ++reg) {
            float vm  = acc1[0][n][reg];
            float h8  = (reg < 12) ? acc1[0][n][reg + 4] : acc1[1][n][reg - 12];
            float sup = (lane < 32) ? h8 : vm;
            float h4  = __shfl_xor(sup, 32);
            float v = kw0[n] * vm + kw1[n] * h4 + kw2[n] * h8;
            float al = a2[(size_t)(t0 + rowof(reg, hi)) * NH + j];
            v = fmaxf(v, 0.f) + al * fminf(v, 0.f);
            int mt2 = reg >> 3;
            int l2  = ((reg & 3) + 8 * ((reg >> 2) & 1) + 4 * hi) | (((lane >> 3) & 3) << 4);
            ys[swz(((mt2 * 16 + jt) * 64 + l2) * 8 + (lane & 7))] = (short)f2bf(v);
        }
    }
    __syncthreads();

    // ---- GEMM2/3: out(32x256) = y(32x512) @ [wres|wskip]; 16x16, verified ----
    f32x4 acc2[2][2];
    #pragma unroll
    for (int m = 0; m < 2; ++m)
        #pragma unroll
        for (int n = 0; n < 2; ++n)
            acc2[m][n] = (f32x4){0.f, 0.f, 0.f, 0.f};

    __builtin_amdgcn_s_setprio(1);    // T5 on the second MFMA cluster
    #pragma unroll
    for (int kt = 0; kt < 16; ++kt) {
        bf16x8 A0 = *reinterpret_cast<const bf16x8*>(&ys[swz(((0 * 16 + kt) * 64 + lane) * 8)]);
        bf16x8 A1 = *reinterpret_cast<const bf16x8*>(&ys[swz(((1 * 16 + kt) * 64 + lane) * 8)]);
        #pragma unroll
        for (int n = 0; n < 2; ++n) {
            int jt = wave * 2 + n;
            bf16x8 Bf = *reinterpret_cast<const bf16x8*>(&wct[((kt * 16 + jt) * 64 + lane) * 8]);
            acc2[0][n] = __builtin_amdgcn_mfma_f32_16x16x32_bf16(A0, Bf, acc2[0][n], 0, 0, 0);
            acc2[1][n] = __builtin_amdgcn_mfma_f32_16x16x32_bf16(A1, Bf, acc2[1][n], 0, 0, 0);
        }
    }
    __builtin_amdgcn_s_setprio(0);

    // ---- epilogue: waves 0-3 -> residual (+x from LDS xs), waves 4-7 -> skip ----
    #pragma unroll
    for (int m = 0; m < 2; ++m) {
        #pragma unroll
        for (int n = 0; n < 2; ++n) {
            int j = wave * 32 + n * 16 + jl;            // [0,256), wave-uniform split
            #pragma unroll
            for (int reg = 0; reg < 4; ++reg) {
                int g = m * 16 + rb + reg;
                size_t t = (size_t)(t0 + g);
                float v = acc2[m][n][reg];
                if (j < 128) {
                    // x from the still-live xs tile: row r4 = g+4, col j
                    int r4   = g + 4;
                    int ladr = (((r4 >> 5) * 8 + (j >> 4)) * 64
                                + ((r4 & 31) + (((j >> 3) & 1) << 5))) * 8 + (j & 7);
                    float xv = bf2f(xs[ladr]);
                    size_t idx = ((size_t)b * NT + t) * NC + j;
                    out[idx] = v + xv;
                } else {
                    size_t idx = ((size_t)b * NT + t) * NC + (j - 128);
                    out[(size_t)NB * NT * NC + idx] = v;
                }
            }
        }
    }
}

extern "C" void kernel_launch(void* const* d_in, const int* in_sizes, int n_in,
                              void* d_out, int out_size, void* d_ws, size_t ws_size,
                              hipStream_t stream) {
    const float* x  = (const float*)d_in[0];
    const float* wb = (const float*)d_in[1];
    const float* a1 = (const float*)d_in[2];
    const float* wd = (const float*)d_in[3];
    const float* a2 = (const float*)d_in[4];
    const float* wr = (const float*)d_in[5];
    const float* wk = (const float*)d_in[6];
    float* out = (float*)d_out;

    short* wbt32 = (short*)d_ws;
    short* wct   = wbt32 + NWBT;

    prep_weights<<<dim3(384), dim3(512), 0, stream>>>(wb, wr, wk, wbt32, wct);
    conv1d_block_mfma<<<dim3(NB * (NT / TB)), dim3(512), 0, stream>>>(
        x, a1, wd, a2, wbt32, wct, out);
}